// Round 6
// baseline (21752.544 us; speedup 1.0000x reference)
//
#include <hip/hip_runtime.h>
#include <math.h>

namespace {

constexpr int TPB  = 1024;
constexpr int NB   = 256;   // batch
constexpr int NT   = 1000;  // time steps
constexpr int NX   = 64;    // state dim
constexpr int NS   = 4;     // control dim
constexpr int DIN  = 68;    // NX + NS
constexpr int HF   = 256;
constexpr int HG   = 128;
constexpr float DTC   = 0.01f;
constexpr float SIGMA = 0.1f;

constexpr int HPAD = 288;   // padded h storage: idx + (idx>>5)*4
constexpr int CH   = 68;    // dW/out chunk row stride

typedef float v2f __attribute__((ext_vector_type(2)));

__device__ __forceinline__ int pmap(int i){ return i + ((i>>5)<<2); }

template<int CTRL>
__device__ __forceinline__ float dpp_add(float x){
    int y = __builtin_amdgcn_update_dpp(0, __float_as_int(x), CTRL, 0xF, 0xF, true);
    return x + __int_as_float(y);
}
// all reductions pure DPP (VALU pipe), results replicated across the group
__device__ __forceinline__ float quad_sum(float x){   // lanes ^1, ^2
    x = dpp_add<0xB1>(x);    // quad_perm [1,0,3,2]
    x = dpp_add<0x4E>(x);    // quad_perm [2,3,0,1]
    return x;
}
__device__ __forceinline__ float red8(float x){       // + lanes ^4
    return dpp_add<0x141>(quad_sum(x));   // row_half_mirror : l ^ 7
}
__device__ __forceinline__ float red16(float x){      // + lanes ^8
    return dpp_add<0x140>(red8(x));       // row_mirror : l ^ 15
}

__device__ __forceinline__ float tanh_fast(float x){
    float e = __expf(2.0f*x);
    float r = __builtin_amdgcn_rcpf(e + 1.0f);
    return __builtin_fmaf(-2.0f, r, 1.0f);
}
__device__ __forceinline__ float softplus_f(float x){
    return fmaxf(x,0.0f) + __logf(1.0f + __expf(-fabsf(x)));
}

__device__ __forceinline__ v2f pkfma(v2f a, v2f b, v2f c){
    return __builtin_elementwise_fma(a, b, c);   // v_pk_fma_f32
}

// One workgroup (1024 threads, 16 waves) = one batch element, all 1000 steps.
// 12 barriers/step; 4 waves/SIMD for latency hiding; reductions all-DPP.
__global__ __launch_bounds__(TPB, 4) void sde_rk4_kernel(
    const float* __restrict__ gIn, const float* __restrict__ gNz,
    const float* __restrict__ Wf1, const float* __restrict__ bf1,
    const float* __restrict__ Wf2, const float* __restrict__ bf2,
    const float* __restrict__ Wf3, const float* __restrict__ bf3,
    const float* __restrict__ Wg1, const float* __restrict__ bg1,
    const float* __restrict__ Wg2, const float* __restrict__ bg2,
    float* __restrict__ gOut)
{
    const int b = blockIdx.x;
    const int t = threadIdx.x;

    __shared__ __align__(16) float s_z[72];        // [X(64), u(4), pad]
    __shared__ __align__(16) float s_h1[HPAD];
    __shared__ __align__(16) float s_h2[HPAD];
    __shared__ __align__(16) float s_hg[HG];
    __shared__ __align__(16) float s_uall[4008];   // u[step][4] (+pad)
    __shared__ __align__(16) float s_dwc[NX*CH];   // dW chunk [x][64]
    __shared__ __align__(16) float s_out[NX*CH];   // out buffer [x][64]

    // ---- thread roles ----
    const int q2  = t & 3;          // L1 k-slice (4-way)
    const int cA  = t >> 2;         // L1 col (256)
    const int k0A = 16*q2;          const int lenA = (q2==3)?20:16;
    const int s3  = t & 7;          // G1 k-slice (8-way)
    const int cG  = t >> 3;         // G1 col (128)
    const int k0G = 8*s3;           const int lenG = (s3==7)?12:8;
    const int s16 = t & 15;         // L2/L3/G2 k-slice (16-way)
    const int g16 = t >> 4;         // group (64)
    const int cB0 = 4*g16;          const int k0B  = 16*s16;   // L2: 4 cols
    const int cC  = g16;            const int k0G2 = 8*s16;    // L3/G2 col
    const int hbase = pmap(k0B);    // shared by L2 h1-read and L3 h2-read
    const bool l16_0 = (s16 == 0);
    const int rD = t>>4, j0D = (t&15)*4;   // dW/out chunk roles (64 x 16x4)

    // ---- weights -> registers (zero-padded slices) ----
    float wf1r[20];
#pragma unroll
    for (int k=0;k<20;++k) wf1r[k] = (k<lenA) ? Wf1[(k0A+k)*HF + cA] : 0.f;
    float wg1r[12];
#pragma unroll
    for (int k=0;k<12;++k) wg1r[k] = (k<lenG) ? Wg1[(k0G+k)*HG + cG] : 0.f;
    v2f wf2r[16][2];
#pragma unroll
    for (int k=0;k<16;++k){
        const float4 wv = *(const float4*)&Wf2[(size_t)(k0B+k)*HF + cB0];
        wf2r[k][0] = (v2f){wv.x, wv.y};
        wf2r[k][1] = (v2f){wv.z, wv.w};
    }
    v2f wf3p[8];
#pragma unroll
    for (int j=0;j<8;++j)
        wf3p[j] = (v2f){ Wf3[(k0B+2*j)*NX + cC], Wf3[(k0B+2*j+1)*NX + cC] };
    float wg2r[8];
#pragma unroll
    for (int k=0;k<8;++k) wg2r[k] = Wg2[(k0G2+k)*NX + cC];

    const float bf1c = bf1[cA];
    const float4 bf2v = *(const float4*)&bf2[cB0];
    const float bf3c = bf3[cC];
    const float bg1c = bg1[cG];
    const float bg2c = bg2[cC];

    const float sq = sqrtf(DTC);
    const float* inB = gIn + (size_t)b*DIN*NT;
    const float* nzB = gNz + (size_t)b*NX*NT;
    float*      outB = gOut + (size_t)b*NX*NT;

    // ---- u sequence -> LDS; initial state ----
    for (int i=t;i<NS*NT; i+=TPB) s_uall[i] = inB[(i&3)*NT + (i>>2)];
    if (t<8)            s_uall[NS*NT+t] = 0.f;
    if (t>=68 && t<72)  s_z[t] = 0.f;
    if (t<4)            s_z[64+t] = inB[t*NT];
    float X = inB[(size_t)(NS+cC)*NT];   // replicated across 16-group
    float kacc = 0.f, gc = 0.f;
    if (l16_0) s_z[cC] = X;
    __syncthreads();

    // ---------- phases ----------
    auto phaseA = [&](bool withG){
        float a0=0.f, a1=0.f;
#pragma unroll
        for (int q=0;q<5;++q){                  // weights zero-padded beyond lenA
            const float4 zv = *(const float4*)&s_z[k0A + 4*q];
            a0 = fmaf(zv.x, wf1r[4*q+0], a0);
            a1 = fmaf(zv.y, wf1r[4*q+1], a1);
            a0 = fmaf(zv.z, wf1r[4*q+2], a0);
            a1 = fmaf(zv.w, wf1r[4*q+3], a1);
        }
        const float r = quad_sum(a0 + a1);
        const float h = tanh_fast(r + bf1c);
        if ((t&3)==0) s_h1[pmap(cA)] = h;
        if (withG){
            float g0=0.f, g1=0.f;
#pragma unroll
            for (int q=0;q<3;++q){              // zero-padded beyond lenG
                const float4 zv = *(const float4*)&s_z[k0G + 4*q];
                g0 = fmaf(zv.x, wg1r[4*q+0], g0);
                g1 = fmaf(zv.y, wg1r[4*q+1], g1);
                g0 = fmaf(zv.z, wg1r[4*q+2], g0);
                g1 = fmaf(zv.w, wg1r[4*q+3], g1);
            }
            const float gr = red8(g0 + g1);
            if ((t&7)==0) s_hg[cG] = tanh_fast(gr + bg1c);
        }
        __syncthreads();
    };

    auto phaseB = [&](bool withG){
        v2f A0={0.f,0.f}, A1={0.f,0.f}, B0={0.f,0.f}, B1={0.f,0.f};
        const float* h1p = &s_h1[hbase];
#pragma unroll
        for (int q=0;q<4;++q){
            const float4 hv = *(const float4*)&h1p[4*q];
            A0 = pkfma((v2f){hv.x,hv.x}, wf2r[4*q+0][0], A0);
            A1 = pkfma((v2f){hv.x,hv.x}, wf2r[4*q+0][1], A1);
            B0 = pkfma((v2f){hv.y,hv.y}, wf2r[4*q+1][0], B0);
            B1 = pkfma((v2f){hv.y,hv.y}, wf2r[4*q+1][1], B1);
            A0 = pkfma((v2f){hv.z,hv.z}, wf2r[4*q+2][0], A0);
            A1 = pkfma((v2f){hv.z,hv.z}, wf2r[4*q+2][1], A1);
            B0 = pkfma((v2f){hv.w,hv.w}, wf2r[4*q+3][0], B0);
            B1 = pkfma((v2f){hv.w,hv.w}, wf2r[4*q+3][1], B1);
        }
        const v2f S0 = A0 + B0, S1 = A1 + B1;
        const float c0 = red16(S0[0]);
        const float c1 = red16(S0[1]);
        const float c2 = red16(S1[0]);
        const float c3 = red16(S1[1]);
        if (withG){
            float g0=0.f, g1=0.f;
            const float4 hv0 = *(const float4*)&s_hg[k0G2];
            const float4 hv1 = *(const float4*)&s_hg[k0G2+4];
            g0 = fmaf(hv0.x, wg2r[0], g0); g1 = fmaf(hv0.y, wg2r[1], g1);
            g0 = fmaf(hv0.z, wg2r[2], g0); g1 = fmaf(hv0.w, wg2r[3], g1);
            g0 = fmaf(hv1.x, wg2r[4], g0); g1 = fmaf(hv1.y, wg2r[5], g1);
            g0 = fmaf(hv1.z, wg2r[6], g0); g1 = fmaf(hv1.w, wg2r[7], g1);
            const float gq = red16(g0 + g1);
            gc = SIGMA*softplus_f(gq + bg2c);    // replicated across 16-group
        }
        float4 hv;
        hv.x = tanh_fast(c0 + bf2v.x);
        hv.y = tanh_fast(c1 + bf2v.y);
        hv.z = tanh_fast(c2 + bf2v.z);
        hv.w = tanh_fast(c3 + bf2v.w);
        if (l16_0) *(float4*)&s_h2[pmap(cB0)] = hv;
        __syncthreads();
    };

    auto phaseC = [&](int ev, int st){
        v2f e0={0.f,0.f}, e1={0.f,0.f};
        const float* h2p = &s_h2[hbase];
#pragma unroll
        for (int q=0;q<4;++q){
            const float4 hv = *(const float4*)&h2p[4*q];
            e0 = pkfma((v2f){hv.x,hv.y}, wf3p[2*q+0], e0);
            e1 = pkfma((v2f){hv.z,hv.w}, wf3p[2*q+1], e1);
        }
        const v2f es = e0 + e1;
        const float kv = red16(es[0] + es[1]) + bf3c;  // replicated
        if (ev==0)      kacc = kv;
        else if (ev==3) kacc += kv;
        else            kacc += 2.0f*kv;
        if (ev<3){
            if (l16_0) s_z[cC] = fmaf((ev==2)?DTC:0.5f*DTC, kv, X);
        } else {
            const int jj = st & 63;
            const float dw = s_dwc[cC*CH + jj];        // broadcast in 16-group
            X = X + (DTC/6.0f)*kacc + gc*dw;           // replicated update
            if (l16_0){
                s_z[cC] = X;
                s_out[cC*CH + jj] = X;
                if (cC < NS) s_z[64+cC] = s_uall[(st+1)*4 + cC];
            }
        }
        __syncthreads();
    };

    // ---------- main loop ----------
#pragma unroll 1
    for (int st=0; st<NT; ++st){
        if ((st & 63) == 0){
            // bulk-load next 64 steps of dW (coalesced float4), scale sqrt(dt)
            const int col = st + j0D;                  // multiple of 4
            float4 v = make_float4(0.f,0.f,0.f,0.f);
            if (col + 3 < NT) v = *(const float4*)&nzB[(size_t)rD*NT + col];
            float* d = &s_dwc[rD*CH + j0D];
            d[0]=v.x*sq; d[1]=v.y*sq; d[2]=v.z*sq; d[3]=v.w*sq;
        }

        phaseA(true);  phaseB(true);  phaseC(0, st);
#pragma unroll
        for (int ev=1; ev<4; ++ev){
            phaseA(false); phaseB(false); phaseC(ev, st);
        }

        if ((st & 63) == 63 || st == NT-1){
            const int st0 = st & ~63;
            const int col = st0 + j0D;
            if (col + 3 <= st)
                *(float4*)&outB[(size_t)rD*NT + col] =
                    *(const float4*)&s_out[rD*CH + j0D];
        }
    }
}

} // namespace

extern "C" void kernel_launch(void* const* d_in, const int* in_sizes, int n_in,
                              void* d_out, int out_size, void* d_ws, size_t ws_size,
                              hipStream_t stream)
{
    const float* Inputs = (const float*)d_in[0];
    const float* noise  = (const float*)d_in[1];
    // d_in[2] = t0 (unused)
    const float* Wf1 = (const float*)d_in[3];
    const float* bf1 = (const float*)d_in[4];
    const float* Wf2 = (const float*)d_in[5];
    const float* bf2 = (const float*)d_in[6];
    const float* Wf3 = (const float*)d_in[7];
    const float* bf3 = (const float*)d_in[8];
    const float* Wg1 = (const float*)d_in[9];
    const float* bg1 = (const float*)d_in[10];
    const float* Wg2 = (const float*)d_in[11];
    const float* bg2 = (const float*)d_in[12];
    float* out = (float*)d_out;

    sde_rk4_kernel<<<dim3(NB), dim3(TPB), 0, stream>>>(
        Inputs, noise, Wf1, bf1, Wf2, bf2, Wf3, bf3, Wg1, bg1, Wg2, bg2, out);
}

// Round 7
// 13180.074 us; speedup vs baseline: 1.6504x; 1.6504x over previous
//
#include <hip/hip_runtime.h>
#include <math.h>

namespace {

constexpr int TPB  = 1024;
constexpr int NB   = 256;   // batch
constexpr int NT   = 1000;  // time steps
constexpr int NX   = 64;    // state dim
constexpr int NS   = 4;     // control dim
constexpr int DIN  = 68;    // NX + NS
constexpr int HF   = 256;
constexpr int HG   = 128;
constexpr float DTC   = 0.01f;
constexpr float SIGMA = 0.1f;

constexpr int HPAD  = 288;  // padded h storage: idx + (idx>>5)*4
constexpr int CH    = 68;   // dW/out chunk row stride
constexpr int WG1LD = 133;  // s_wg1 row stride (odd -> <=2-way bank conflicts)
constexpr int WG2LD = 136;  // s_wg2t row stride (16B-aligned rows)

typedef float v2f __attribute__((ext_vector_type(2)));

__device__ __forceinline__ int pmap(int i){ return i + ((i>>5)<<2); }

template<int CTRL>
__device__ __forceinline__ float dpp_add(float x){
    int y = __builtin_amdgcn_update_dpp(0, __float_as_int(x), CTRL, 0xF, 0xF, true);
    return x + __int_as_float(y);
}
// all reductions pure DPP (VALU pipe), results replicated across the group
__device__ __forceinline__ float quad_sum(float x){   // lanes ^1, ^2
    x = dpp_add<0xB1>(x);    // quad_perm [1,0,3,2]
    x = dpp_add<0x4E>(x);    // quad_perm [2,3,0,1]
    return x;
}
__device__ __forceinline__ float red8(float x){       // + lanes ^4
    return dpp_add<0x141>(quad_sum(x));   // row_half_mirror : l ^ 7
}
__device__ __forceinline__ float red16(float x){      // + lanes ^8
    return dpp_add<0x140>(red8(x));       // row_mirror : l ^ 15
}

__device__ __forceinline__ float tanh_fast(float x){
    float e = __expf(2.0f*x);
    float r = __builtin_amdgcn_rcpf(e + 1.0f);
    return __builtin_fmaf(-2.0f, r, 1.0f);
}
__device__ __forceinline__ float softplus_f(float x){
    return fmaxf(x,0.0f) + __logf(1.0f + __expf(-fabsf(x)));
}

__device__ __forceinline__ v2f pkfma(v2f a, v2f b, v2f c){
    return __builtin_elementwise_fma(a, b, c);   // v_pk_fma_f32
}

// One workgroup (1024 threads, 16 waves = 4/SIMD) = one batch element.
// F-weights register-resident (~100 floats/thread, fits 128-VGPR cap);
// G-weights in LDS (touched once/step). 12 barriers/step, all-DPP reductions.
__global__ __launch_bounds__(TPB, 4) void sde_rk4_kernel(
    const float* __restrict__ gIn, const float* __restrict__ gNz,
    const float* __restrict__ Wf1, const float* __restrict__ bf1,
    const float* __restrict__ Wf2, const float* __restrict__ bf2,
    const float* __restrict__ Wf3, const float* __restrict__ bf3,
    const float* __restrict__ Wg1, const float* __restrict__ bg1,
    const float* __restrict__ Wg2, const float* __restrict__ bg2,
    float* __restrict__ gOut)
{
    const int b = blockIdx.x;
    const int t = threadIdx.x;

    __shared__ __align__(16) float s_z[72];        // [X(64), u(4), pad=0]
    __shared__ __align__(16) float s_h1[HPAD];
    __shared__ __align__(16) float s_h2[HPAD];
    __shared__ __align__(16) float s_hg[HG];
    __shared__ __align__(16) float s_uall[4008];   // u[step][4] (+pad)
    __shared__ __align__(16) float s_dwc[NX*CH];   // dW chunk [x][64]
    __shared__ __align__(16) float s_out[NX*CH];   // out buffer [x][64]
    __shared__ __align__(16) float s_wg1[72*WG1LD];   // [k][c], rows 68..71 = 0
    __shared__ __align__(16) float s_wg2t[NX*WG2LD];  // [c][k] transposed

    // ---- thread roles ----
    const int q2  = t & 3;          // L1 k-slice (4-way)
    const int cA  = t >> 2;         // L1 col (256)
    const int k0A = 16*q2;          const int lenA = (q2==3)?20:16;
    const int s8g = t & 7;          // G1 k-slice (8-way, 9 rows each, padded)
    const int cG  = t >> 3;         // G1 col (128)
    const int k0G = 9*s8g;
    const int s16 = t & 15;         // L2/L3/G2 k-slice (16-way)
    const int g16 = t >> 4;         // group (64)
    const int cB0 = 4*g16;          const int k0B  = 16*s16;   // L2: 4 cols
    const int cC  = g16;            const int k0G2 = 8*s16;    // L3/G2 col
    const int hbase = pmap(k0B);    // shared by L2 h1-read and L3 h2-read
    const bool l16_0 = (s16 == 0);
    const int rD = t>>4, j0D = (t&15)*4;   // dW/out chunk roles (64 x 16x4)

    // ---- F-weights -> registers (zero-padded slices) ----
    float wf1r[20];
#pragma unroll
    for (int k=0;k<20;++k) wf1r[k] = (k<lenA) ? Wf1[(k0A+k)*HF + cA] : 0.f;
    v2f wf2r[16][2];
#pragma unroll
    for (int k=0;k<16;++k){
        const float4 wv = *(const float4*)&Wf2[(size_t)(k0B+k)*HF + cB0];
        wf2r[k][0] = (v2f){wv.x, wv.y};
        wf2r[k][1] = (v2f){wv.z, wv.w};
    }
    v2f wf3p[8];
#pragma unroll
    for (int j=0;j<8;++j)
        wf3p[j] = (v2f){ Wf3[(k0B+2*j)*NX + cC], Wf3[(k0B+2*j+1)*NX + cC] };

    const float bf1c = bf1[cA];
    const float4 bf2v = *(const float4*)&bf2[cB0];
    const float bf3c = bf3[cC];
    const float bg1c = bg1[cG];
    const float bg2c = bg2[cC];

    const float sq = sqrtf(DTC);
    const float* inB = gIn + (size_t)b*DIN*NT;
    const float* nzB = gNz + (size_t)b*NX*NT;
    float*      outB = gOut + (size_t)b*NX*NT;

    // ---- G-weights -> LDS; u sequence -> LDS; initial state ----
    for (int i=t;i<72*HG;i+=TPB){
        const int k=i>>7, c=i&(HG-1);
        s_wg1[k*WG1LD+c] = (k<DIN) ? Wg1[k*HG+c] : 0.f;
    }
    for (int i=t;i<HG*NX;i+=TPB){
        const int k=i>>6, c=i&(NX-1);
        s_wg2t[c*WG2LD+k] = Wg2[i];
    }
    for (int i=t;i<NS*NT; i+=TPB) s_uall[i] = inB[(i&3)*NT + (i>>2)];
    if (t<8)            s_uall[NS*NT+t] = 0.f;
    if (t>=68 && t<72)  s_z[t] = 0.f;
    if (t<4)            s_z[64+t] = inB[t*NT];
    float X = inB[(size_t)(NS+cC)*NT];   // replicated across 16-group
    float kacc = 0.f, gc = 0.f;
    if (l16_0) s_z[cC] = X;
    __syncthreads();

    // ---------- phases ----------
    auto phaseA = [&](bool withG){
        float a0=0.f, a1=0.f;
#pragma unroll
        for (int q=0;q<5;++q){                  // weights zero-padded beyond lenA
            const float4 zv = *(const float4*)&s_z[k0A + 4*q];
            a0 = fmaf(zv.x, wf1r[4*q+0], a0);
            a1 = fmaf(zv.y, wf1r[4*q+1], a1);
            a0 = fmaf(zv.z, wf1r[4*q+2], a0);
            a1 = fmaf(zv.w, wf1r[4*q+3], a1);
        }
        const float r = quad_sum(a0 + a1);
        if ((t&3)==0) s_h1[pmap(cA)] = tanh_fast(r + bf1c);
        if (withG){
            float g0=0.f, g1=0.f;
#pragma unroll
            for (int i=0;i<9;++i){              // rows 68..71 are zero (s_z too)
                const float zk = s_z[k0G+i];
                const float wk = s_wg1[(k0G+i)*WG1LD + cG];
                if (i & 1) g1 = fmaf(zk, wk, g1); else g0 = fmaf(zk, wk, g0);
            }
            const float gr = red8(g0 + g1);
            if ((t&7)==0) s_hg[cG] = tanh_fast(gr + bg1c);
        }
        __syncthreads();
    };

    auto phaseB = [&](bool withG){
        v2f A0={0.f,0.f}, A1={0.f,0.f};
        const float* h1p = &s_h1[hbase];
#pragma unroll
        for (int q=0;q<4;++q){
            const float4 hv = *(const float4*)&h1p[4*q];
            A0 = pkfma((v2f){hv.x,hv.x}, wf2r[4*q+0][0], A0);
            A1 = pkfma((v2f){hv.x,hv.x}, wf2r[4*q+0][1], A1);
            A0 = pkfma((v2f){hv.y,hv.y}, wf2r[4*q+1][0], A0);
            A1 = pkfma((v2f){hv.y,hv.y}, wf2r[4*q+1][1], A1);
            A0 = pkfma((v2f){hv.z,hv.z}, wf2r[4*q+2][0], A0);
            A1 = pkfma((v2f){hv.z,hv.z}, wf2r[4*q+2][1], A1);
            A0 = pkfma((v2f){hv.w,hv.w}, wf2r[4*q+3][0], A0);
            A1 = pkfma((v2f){hv.w,hv.w}, wf2r[4*q+3][1], A1);
        }
        const float c0 = red16(A0[0]);
        const float c1 = red16(A0[1]);
        const float c2 = red16(A1[0]);
        const float c3 = red16(A1[1]);
        if (withG){
            const float4 w0 = *(const float4*)&s_wg2t[cC*WG2LD + k0G2];
            const float4 w1 = *(const float4*)&s_wg2t[cC*WG2LD + k0G2 + 4];
            const float4 h0 = *(const float4*)&s_hg[k0G2];
            const float4 h1v = *(const float4*)&s_hg[k0G2+4];
            float g0=0.f, g1=0.f;
            g0 = fmaf(h0.x, w0.x, g0);  g1 = fmaf(h0.y, w0.y, g1);
            g0 = fmaf(h0.z, w0.z, g0);  g1 = fmaf(h0.w, w0.w, g1);
            g0 = fmaf(h1v.x, w1.x, g0); g1 = fmaf(h1v.y, w1.y, g1);
            g0 = fmaf(h1v.z, w1.z, g0); g1 = fmaf(h1v.w, w1.w, g1);
            const float gq = red16(g0 + g1);
            gc = SIGMA*softplus_f(gq + bg2c);    // replicated across 16-group
        }
        float4 hv;
        hv.x = tanh_fast(c0 + bf2v.x);
        hv.y = tanh_fast(c1 + bf2v.y);
        hv.z = tanh_fast(c2 + bf2v.z);
        hv.w = tanh_fast(c3 + bf2v.w);
        if (l16_0) *(float4*)&s_h2[pmap(cB0)] = hv;
        __syncthreads();
    };

    auto phaseC = [&](int ev, int st){
        v2f e0={0.f,0.f}, e1={0.f,0.f};
        const float* h2p = &s_h2[hbase];
#pragma unroll
        for (int q=0;q<4;++q){
            const float4 hv = *(const float4*)&h2p[4*q];
            e0 = pkfma((v2f){hv.x,hv.y}, wf3p[2*q+0], e0);
            e1 = pkfma((v2f){hv.z,hv.w}, wf3p[2*q+1], e1);
        }
        const v2f es = e0 + e1;
        const float kv = red16(es[0] + es[1]) + bf3c;  // replicated
        if (ev==0)      kacc = kv;
        else if (ev==3) kacc += kv;
        else            kacc += 2.0f*kv;
        if (ev<3){
            if (l16_0) s_z[cC] = fmaf((ev==2)?DTC:0.5f*DTC, kv, X);
        } else {
            const int jj = st & 63;
            const float dw = s_dwc[cC*CH + jj];        // broadcast in 16-group
            X = X + (DTC/6.0f)*kacc + gc*dw;           // replicated update
            if (l16_0){
                s_z[cC] = X;
                s_out[cC*CH + jj] = X;
                if (cC < NS) s_z[64+cC] = s_uall[(st+1)*4 + cC];
            }
        }
        __syncthreads();
    };

    // ---------- main loop ----------
#pragma unroll 1
    for (int st=0; st<NT; ++st){
        if ((st & 63) == 0){
            // bulk-load next 64 steps of dW (coalesced float4), scale sqrt(dt)
            const int col = st + j0D;                  // multiple of 4
            float4 v = make_float4(0.f,0.f,0.f,0.f);
            if (col + 3 < NT) v = *(const float4*)&nzB[(size_t)rD*NT + col];
            float* d = &s_dwc[rD*CH + j0D];
            d[0]=v.x*sq; d[1]=v.y*sq; d[2]=v.z*sq; d[3]=v.w*sq;
        }

        phaseA(true);  phaseB(true);  phaseC(0, st);
#pragma unroll
        for (int ev=1; ev<4; ++ev){
            phaseA(false); phaseB(false); phaseC(ev, st);
        }

        if ((st & 63) == 63 || st == NT-1){
            const int st0 = st & ~63;
            const int col = st0 + j0D;
            if (col + 3 <= st)
                *(float4*)&outB[(size_t)rD*NT + col] =
                    *(const float4*)&s_out[rD*CH + j0D];
        }
    }
}

} // namespace

extern "C" void kernel_launch(void* const* d_in, const int* in_sizes, int n_in,
                              void* d_out, int out_size, void* d_ws, size_t ws_size,
                              hipStream_t stream)
{
    const float* Inputs = (const float*)d_in[0];
    const float* noise  = (const float*)d_in[1];
    // d_in[2] = t0 (unused)
    const float* Wf1 = (const float*)d_in[3];
    const float* bf1 = (const float*)d_in[4];
    const float* Wf2 = (const float*)d_in[5];
    const float* bf2 = (const float*)d_in[6];
    const float* Wf3 = (const float*)d_in[7];
    const float* bf3 = (const float*)d_in[8];
    const float* Wg1 = (const float*)d_in[9];
    const float* bg1 = (const float*)d_in[10];
    const float* Wg2 = (const float*)d_in[11];
    const float* bg2 = (const float*)d_in[12];
    float* out = (float*)d_out;

    sde_rk4_kernel<<<dim3(NB), dim3(TPB), 0, stream>>>(
        Inputs, noise, Wf1, bf1, Wf2, bf2, Wf3, bf3, Wg1, bg1, Wg2, bg2, out);
}